// Round 8
// baseline (178.560 us; speedup 1.0000x reference)
//
#include <hip/hip_runtime.h>
#include <hip/hip_bf16.h>
#include <math.h>

#define ALPHA 0.2f
#define ACVT 0.01f

typedef __attribute__((ext_vector_type(8))) __bf16 bf16x8;
typedef __attribute__((ext_vector_type(4))) __bf16 bf16x4;
typedef __attribute__((ext_vector_type(4))) float f32x4;

__device__ __forceinline__ bf16x8 cvt8(const float* p) {
    float4 v0 = *(const float4*)p;
    float4 v1 = *(const float4*)(p + 4);
    bf16x8 o;
    o[0] = (__bf16)v0.x; o[1] = (__bf16)v0.y; o[2] = (__bf16)v0.z; o[3] = (__bf16)v0.w;
    o[4] = (__bf16)v1.x; o[5] = (__bf16)v1.y; o[6] = (__bf16)v1.z; o[7] = (__bf16)v1.w;
    return o;
}

// ============================================================================
// GEMM1: HT[(b*8+h)*64+d][n] = sum_f X[b*512+n][f] * Wt[h*64+d][f]  (bf16 out)
// XCD-chunked swizzle; HT store transposed through padded LDS (coalesced).
// Fused e1/e2. BM=BN=128, KC=64. grid 512, 256 thr = 4 waves 2x2.
// ============================================================================
__global__ __launch_bounds__(256) void gemm1_f(
    const float* __restrict__ X, const float* __restrict__ Wt,
    __bf16* __restrict__ HT,
    const float* __restrict__ a1, const float* __restrict__ a2,
    float* __restrict__ E1, float* __restrict__ E2) {
    __shared__ char As[128 * 128];
    __shared__ char Bs[128 * 128];
    __shared__ char Tt[128 * 264];
    const int tid = threadIdx.x;
    const int w = tid >> 6, lane = tid & 63;
    const int wm = w >> 1, wn = w & 1;
    const int r = lane & 15, g = lane >> 4;
    const int L = blockIdx.x;
    const int W = (L & 7) * 64 + (L >> 3);
    const int m_tile = W >> 2, n_tile = W & 3;
    const int m0 = m_tile * 128;
    const int n0 = n_tile * 128;

    f32x4 acc[4][4];
#pragma unroll
    for (int mt = 0; mt < 4; ++mt)
#pragma unroll
        for (int nt = 0; nt < 4; ++nt) {
            acc[mt][nt][0] = 0.f; acc[mt][nt][1] = 0.f;
            acc[mt][nt][2] = 0.f; acc[mt][nt][3] = 0.f;
        }

    const int sr = tid >> 3;
    const int c8 = (tid & 7) * 8;

    for (int k0 = 0; k0 < 256; k0 += 64) {
        __syncthreads();
#pragma unroll
        for (int i = 0; i < 4; ++i) {
            int row = sr + i * 32;
            bf16x8 va = cvt8(X + (size_t)(m0 + row) * 256 + k0 + c8);
            *(bf16x8*)(As + row * 128 + ((c8 * 2) ^ ((row & 7) << 4))) = va;
            bf16x8 vb = cvt8(Wt + (size_t)(n0 + row) * 256 + k0 + c8);
            *(bf16x8*)(Bs + row * 128 + ((c8 * 2) ^ ((row & 7) << 4))) = vb;
        }
        __syncthreads();
#pragma unroll
        for (int kk = 0; kk < 64; kk += 32) {
            bf16x8 af[4], bfv[4];
#pragma unroll
            for (int mt = 0; mt < 4; ++mt) {
                int row = wm * 64 + mt * 16 + r;
                af[mt] = *(const bf16x8*)(As + row * 128 +
                                          (((kk + g * 8) * 2) ^ ((row & 7) << 4)));
            }
#pragma unroll
            for (int nt = 0; nt < 4; ++nt) {
                int row = wn * 64 + nt * 16 + r;
                bfv[nt] = *(const bf16x8*)(Bs + row * 128 +
                                           (((kk + g * 8) * 2) ^ ((row & 7) << 4)));
            }
#pragma unroll
            for (int mt = 0; mt < 4; ++mt)
#pragma unroll
                for (int nt = 0; nt < 4; ++nt)
                    acc[mt][nt] = __builtin_amdgcn_mfma_f32_16x16x32_bf16(
                        af[mt], bfv[nt], acc[mt][nt], 0, 0, 0);
        }
    }

#pragma unroll
    for (int mt = 0; mt < 4; ++mt) {
        int node = wm * 64 + mt * 16 + g * 4;
#pragma unroll
        for (int nt = 0; nt < 4; ++nt) {
            int d_blk = wn * 64 + nt * 16 + r;
            bf16x4 pv;
#pragma unroll
            for (int reg = 0; reg < 4; ++reg) pv[reg] = (__bf16)acc[mt][nt][reg];
            *(bf16x4*)(Tt + d_blk * 264 + node * 2) = pv;
        }
    }
    __syncthreads();
    {
        const int b = m0 >> 9, nn = m0 & 511;
        const int h0 = n_tile * 2;
#pragma unroll
        for (int i = 0; i < 8; ++i) {
            int d_row = (tid >> 4) + i * 16;
            int hrow = (b * 8 + h0 + (d_row >> 6)) * 64 + (d_row & 63);
            bf16x8 v = *(const bf16x8*)(Tt + d_row * 264 + (tid & 15) * 16);
            *(bf16x8*)(HT + (size_t)hrow * 512 + nn + (tid & 15) * 8) = v;
        }
    }
    const int h = n_tile * 2 + wn;
    float w1[4], w2[4];
#pragma unroll
    for (int nt = 0; nt < 4; ++nt) {
        w1[nt] = a1[h * 64 + nt * 16 + r];
        w2[nt] = a2[h * 64 + nt * 16 + r];
    }
#pragma unroll
    for (int mt = 0; mt < 4; ++mt)
#pragma unroll
        for (int reg = 0; reg < 4; ++reg) {
            float s1 = 0.f, s2 = 0.f;
#pragma unroll
            for (int nt = 0; nt < 4; ++nt) {
                s1 += acc[mt][nt][reg] * w1[nt];
                s2 += acc[mt][nt][reg] * w2[nt];
            }
#pragma unroll
            for (int off = 1; off <= 8; off <<= 1) {
                s1 += __shfl_xor(s1, off, 64);
                s2 += __shfl_xor(s2, off, 64);
            }
            if (r == 0) {
                int m = m0 + wm * 64 + mt * 16 + g * 4 + reg;
                int b = m >> 9, n = m & 511;
                E1[(size_t)(b * 8 + h) * 512 + n] = s1;
                E2[(size_t)(b * 8 + h) * 512 + n] = s2;
            }
        }
}

// ============================================================================
// FUSED attention + GEMM2. Block = (b, 64-row slice e8, head-half hh2).
// 256 thr = 4 waves x 16 rows. Loop 4 heads: PV-MFMA (B-frags from global
// HT w/ prefetch), normalize+leaky, re-fragment via 2KB per-wave LDS, MFMA
// vs LDS-staged Wo slice into 128-wide H2 accumulator. Emits H2/F1/F2
// partials per head-half. grid 512.
// ============================================================================
__global__ __launch_bounds__(256) void attnfused(
    const __bf16* __restrict__ HT, const float* __restrict__ E1,
    const float* __restrict__ E2, const float* __restrict__ Wo,
    const float* __restrict__ a1o, const float* __restrict__ a2o,
    __bf16* __restrict__ H2P, float* __restrict__ F1P, float* __restrict__ F2P) {
    __shared__ char Wos[128 * 128];   // 16 KB [cc][d] bf16, swz
    __shared__ float e1s[4][512];     // 8 KB
    __shared__ char pbuf[4][2048];    // per-wave 16x64 bf16, swz
    __shared__ float e1mx[4];
    __shared__ float zrow[4][16];

    const int bid = blockIdx.x;
    const int b = bid >> 4, e8 = (bid >> 1) & 7, hh2 = bid & 1;
    const int j0 = e8 * 64;
    const int tid = threadIdx.x;
    const int w = tid >> 6, lane = tid & 63;
    const int r = lane & 15, g = lane >> 4;

    for (int i = tid; i < 2048; i += 256) {
        int hh = i >> 9;
        e1s[hh][i & 511] = E1[((size_t)(b * 8 + hh2 * 4 + hh)) * 512 + (i & 511)];
    }
    __syncthreads();
    {   // wave w reduces local head w
        float m = -1e30f;
#pragma unroll
        for (int i = 0; i < 8; ++i) m = fmaxf(m, e1s[w][lane + 64 * i]);
#pragma unroll
        for (int off = 32; off >= 1; off >>= 1) m = fmaxf(m, __shfl_xor(m, off, 64));
        if (lane == 0) e1mx[w] = m;
    }

    f32x4 h2acc[8];
#pragma unroll
    for (int ct = 0; ct < 8; ++ct) {
        h2acc[ct][0] = 0.f; h2acc[ct][1] = 0.f; h2acc[ct][2] = 0.f; h2acc[ct][3] = 0.f;
    }

    const int row_j = j0 + w * 16 + r;
    char* pb = pbuf[w];

    for (int hh = 0; hh < 4; ++hh) {
        const int h = hh2 * 4 + hh;
        const size_t bh = (size_t)b * 8 + h;
        __syncthreads();  // prior Wos reads done; e1mx visible (hh==0)
        {   // stage Wo slice [128 c][64 d] -> bf16
            int c = tid >> 1, dh = tid & 1;
            const float* wsrc = Wo + (size_t)c * 512 + h * 64 + dh * 32;
#pragma unroll
            for (int q = 0; q < 4; ++q) {
                bf16x8 v = cvt8(wsrc + q * 8);
                *(bf16x8*)(Wos + c * 128 + (((dh * 32 + q * 8) * 2) ^ ((c & 7) << 4))) = v;
            }
        }
        __syncthreads();

        const float ee2 = E2[bh * 512 + row_j];
        float mml;
        { float s = e1mx[hh] + ee2; mml = fmaxf(s, ALPHA * s); }

        f32x4 acc[4];
#pragma unroll
        for (int nt = 0; nt < 4; ++nt) {
            acc[nt][0] = 0.f; acc[nt][1] = 0.f; acc[nt][2] = 0.f; acc[nt][3] = 0.f;
        }
        float zac = 0.f;

        const __bf16* hb = HT + bh * 32768;
        bf16x8 cur[4], nxt[4];
#pragma unroll
        for (int nt = 0; nt < 4; ++nt)
            cur[nt] = *(const bf16x8*)(hb + (size_t)(nt * 16 + r) * 512 + g * 8);

        for (int c = 0; c < 16; ++c) {
            if (c < 15) {
#pragma unroll
                for (int nt = 0; nt < 4; ++nt)
                    nxt[nt] = *(const bf16x8*)(hb + (size_t)(nt * 16 + r) * 512 +
                                               (c + 1) * 32 + g * 8);
            }
            const float* ep = &e1s[hh][c * 32 + g * 8];
            float4 ea = *(const float4*)(ep);
            float4 eb = *(const float4*)(ep + 4);
            float e1c[8] = {ea.x, ea.y, ea.z, ea.w, eb.x, eb.y, eb.z, eb.w};
            bf16x8 af;
            float zp = 0.f;
#pragma unroll
            for (int q = 0; q < 8; ++q) {
                float s = e1c[q] + ee2;
                s = fmaxf(s, ALPHA * s);
                float p = __expf(s - mml);
                zp += p;
                af[q] = (__bf16)p;
            }
            zac += zp;
#pragma unroll
            for (int nt = 0; nt < 4; ++nt)
                acc[nt] = __builtin_amdgcn_mfma_f32_16x16x32_bf16(af, cur[nt], acc[nt], 0, 0, 0);
            if (c < 15) {
#pragma unroll
                for (int nt = 0; nt < 4; ++nt) cur[nt] = nxt[nt];
            }
        }

        float z = zac;
        z += __shfl_xor(z, 16, 64);
        z += __shfl_xor(z, 32, 64);
        if (g == 0) zrow[w][r] = 1.f / z;

        // normalize + leaky -> per-wave pbuf (bf16, swizzled)
#pragma unroll
        for (int reg = 0; reg < 4; ++reg) {
            int row = g * 4 + reg;
            float zi = zrow[w][row];
#pragma unroll
            for (int nt = 0; nt < 4; ++nt) {
                float v = acc[nt][reg] * zi;
                v = fmaxf(v, ACVT * v);
                *(__bf16*)(pb + ((row * 128 + (nt * 16 + r) * 2) ^ ((row & 7) << 4))) =
                    (__bf16)v;
            }
        }
        // second GEMM: H2 += OLb(16xk64) * Wos(128xk64)^T
#pragma unroll
        for (int ks = 0; ks < 2; ++ks) {
            bf16x8 pa = *(const bf16x8*)(pb + ((r * 128 + (ks * 32 + g * 8) * 2) ^
                                               ((r & 7) << 4)));
#pragma unroll
            for (int ct = 0; ct < 8; ++ct) {
                int cc = ct * 16 + r;
                bf16x8 wf = *(const bf16x8*)(Wos + cc * 128 +
                                             (((ks * 32 + g * 8) * 2) ^ ((cc & 7) << 4)));
                h2acc[ct] = __builtin_amdgcn_mfma_f32_16x16x32_bf16(pa, wf, h2acc[ct], 0, 0, 0);
            }
        }
    }

    // ---- epilogue: F1/F2 partials + H2 partial ----
    float w1[8], w2[8];
#pragma unroll
    for (int ct = 0; ct < 8; ++ct) {
        w1[ct] = a1o[ct * 16 + r];
        w2[ct] = a2o[ct * 16 + r];
    }
#pragma unroll
    for (int reg = 0; reg < 4; ++reg) {
        float s1 = 0.f, s2 = 0.f;
#pragma unroll
        for (int ct = 0; ct < 8; ++ct) {
            s1 += h2acc[ct][reg] * w1[ct];
            s2 += h2acc[ct][reg] * w2[ct];
        }
#pragma unroll
        for (int off = 1; off <= 8; off <<= 1) {
            s1 += __shfl_xor(s1, off, 64);
            s2 += __shfl_xor(s2, off, 64);
        }
        if (r == 0) {
            int m = b * 512 + j0 + w * 16 + g * 4 + reg;
            F1P[hh2 * 16384 + m] = s1;
            F2P[hh2 * 16384 + m] = s2;
        }
    }
    __bf16* hp = H2P + (size_t)hh2 * 2097152 + ((size_t)b * 512 + j0 + w * 16) * 128;
#pragma unroll
    for (int reg = 0; reg < 4; ++reg)
#pragma unroll
        for (int ct = 0; ct < 8; ++ct)
            hp[(size_t)(g * 4 + reg) * 128 + ct * 16 + r] = (__bf16)h2acc[ct][reg];
}

// ============================================================================
// zw: per (b, jc): partial w[k] = sum_{j in chunk} softmax_k(leaky(f1+f2))[j,k]
// F1/F2 come as two head-half partials.
// ============================================================================
__global__ __launch_bounds__(256) void zw_k(const float* __restrict__ F1P,
                                            const float* __restrict__ F2P,
                                            float* __restrict__ WP) {
    __shared__ float f1s[512], f2s[512];
    __shared__ float wpart[4][512];
    __shared__ float redm[256];
    const int b = blockIdx.x >> 4, jc = blockIdx.x & 15;
    const int tid = threadIdx.x;
    const int w = tid >> 6, lane = tid & 63;

    for (int i = tid; i < 512; i += 256) {
        f1s[i] = F1P[(size_t)b * 512 + i] + F1P[16384 + (size_t)b * 512 + i];
        f2s[i] = F2P[(size_t)b * 512 + i] + F2P[16384 + (size_t)b * 512 + i];
    }
#pragma unroll
    for (int i = 0; i < 8; ++i) wpart[w][lane + 64 * i] = 0.f;
    __syncthreads();
    redm[tid] = fmaxf(f1s[tid], f1s[tid + 256]);
    __syncthreads();
    if (tid < 64) {
        float m = fmaxf(fmaxf(redm[tid], redm[tid + 64]), fmaxf(redm[tid + 128], redm[tid + 192]));
#pragma unroll
        for (int off = 32; off >= 1; off >>= 1) m = fmaxf(m, __shfl_xor(m, off, 64));
        if (tid == 0) redm[0] = m;
    }
    __syncthreads();
    const float f1m = redm[0];

    for (int jj = 0; jj < 8; ++jj) {
        int j = jc * 32 + w * 8 + jj;
        float f2j = f2s[j];
        float sj = f1m + f2j;
        float mj = fmaxf(sj, ALPHA * sj);
        float pv[8];
        float z = 0.f;
#pragma unroll
        for (int i = 0; i < 8; ++i) {
            float s = f1s[lane + 64 * i] + f2j;
            s = fmaxf(s, ALPHA * s);
            float p = __expf(s - mj);
            pv[i] = p;
            z += p;
        }
#pragma unroll
        for (int off = 32; off >= 1; off >>= 1) z += __shfl_xor(z, off, 64);
        float inv = 1.f / z;
#pragma unroll
        for (int i = 0; i < 8; ++i) wpart[w][lane + 64 * i] += pv[i] * inv;
    }
    __syncthreads();
    for (int i = tid; i < 512; i += 256)
        WP[(size_t)(b * 16 + jc) * 512 + i] =
            wpart[0][i] + wpart[1][i] + wpart[2][i] + wpart[3][i];
}

// ============================================================================
// finalv: per b: w = sum WP; v = (w/512) . (H2P0+H2P1); out = normalize(v Wl^T + bl)
// ============================================================================
__global__ __launch_bounds__(512) void finalv_k(const float* __restrict__ WP,
                                                const __bf16* __restrict__ H2P,
                                                const float* __restrict__ Wl,
                                                const float* __restrict__ bl,
                                                float* __restrict__ out) {
    __shared__ float wsL[512];
    __shared__ float part[4][128];
    __shared__ float vs[128];
    __shared__ float fo_s[128];
    __shared__ float r0;
    const int b = blockIdx.x, tid = threadIdx.x;
    {
        float s = 0.f;
#pragma unroll
        for (int jc = 0; jc < 16; ++jc) s += WP[(size_t)(b * 16 + jc) * 512 + tid];
        wsL[tid] = s;
    }
    __syncthreads();
    {
        const int q = tid >> 7, d = tid & 127;
        const __bf16* h2p = H2P + ((size_t)b * 512 + q * 128) * 128 + d;
        const __bf16* h2q = h2p + 2097152;
        float acc = 0.f;
#pragma unroll 8
        for (int i = 0; i < 128; ++i)
            acc += wsL[q * 128 + i] *
                   ((float)h2p[(size_t)i * 128] + (float)h2q[(size_t)i * 128]);
        part[q][d] = acc;
    }
    __syncthreads();
    if (tid < 128)
        vs[tid] = (part[0][tid] + part[1][tid] + part[2][tid] + part[3][tid]) * (1.f / 512.f);
    __syncthreads();
    if (tid < 128) {
        float fo = bl[tid];
        const float* wl = Wl + (size_t)tid * 128;
#pragma unroll 4
        for (int d = 0; d < 128; d += 4)
            fo += vs[d] * wl[d] + vs[d + 1] * wl[d + 1] + vs[d + 2] * wl[d + 2] +
                  vs[d + 3] * wl[d + 3];
        fo_s[tid] = fo;
    }
    __syncthreads();
    if (tid < 64) {
        float s = fo_s[tid] * fo_s[tid] + fo_s[tid + 64] * fo_s[tid + 64];
#pragma unroll
        for (int off = 32; off >= 1; off >>= 1) s += __shfl_xor(s, off, 64);
        if (tid == 0) r0 = s;
    }
    __syncthreads();
    float inv = 1.f / fmaxf(sqrtf(r0), 1e-12f);
    if (tid < 128) out[(size_t)b * 128 + tid] = fo_s[tid] * inv;
}

extern "C" void kernel_launch(void* const* d_in, const int* in_sizes, int n_in,
                              void* d_out, int out_size, void* d_ws, size_t ws_size,
                              hipStream_t stream) {
    const float* X = (const float*)d_in[0];
    const float* Wt = (const float*)d_in[1];
    const float* a1 = (const float*)d_in[2];
    const float* a2 = (const float*)d_in[3];
    const float* Wo = (const float*)d_in[4];
    const float* a1o = (const float*)d_in[5];
    const float* a2o = (const float*)d_in[6];
    const float* Wl = (const float*)d_in[7];
    const float* bl = (const float*)d_in[8];
    float* out = (float*)d_out;

    char* p = (char*)d_ws;
    __bf16* HT = (__bf16*)p;  p += (size_t)8388608 * 2;    // 16 MB
    float* E1 = (float*)p;    p += (size_t)131072 * 4;
    float* E2 = (float*)p;    p += (size_t)131072 * 4;
    __bf16* H2P = (__bf16*)p; p += (size_t)2 * 2097152 * 2;  // 8 MB (2 halves)
    float* F1P = (float*)p;   p += (size_t)2 * 16384 * 4;
    float* F2P = (float*)p;   p += (size_t)2 * 16384 * 4;
    float* WP = (float*)p;    p += (size_t)262144 * 4;     // 1 MB

    gemm1_f<<<512, 256, 0, stream>>>(X, Wt, HT, a1, a2, E1, E2);
    attnfused<<<512, 256, 0, stream>>>(HT, E1, E2, Wo, a1o, a2o, H2P, F1P, F2P);
    zw_k<<<512, 256, 0, stream>>>(F1P, F2P, WP);
    finalv_k<<<32, 512, 0, stream>>>(WP, H2P, Wl, bl, out);
}

// Round 9
// 145.747 us; speedup vs baseline: 1.2251x; 1.2251x over previous
//
#include <hip/hip_runtime.h>
#include <hip/hip_bf16.h>
#include <math.h>

#define ALPHA 0.2f
#define ACVT 0.01f

typedef __attribute__((ext_vector_type(8))) __bf16 bf16x8;
typedef __attribute__((ext_vector_type(4))) __bf16 bf16x4;
typedef __attribute__((ext_vector_type(4))) float f32x4;

__device__ __forceinline__ bf16x8 cvt8(const float* p) {
    float4 v0 = *(const float4*)p;
    float4 v1 = *(const float4*)(p + 4);
    bf16x8 o;
    o[0] = (__bf16)v0.x; o[1] = (__bf16)v0.y; o[2] = (__bf16)v0.z; o[3] = (__bf16)v0.w;
    o[4] = (__bf16)v1.x; o[5] = (__bf16)v1.y; o[6] = (__bf16)v1.z; o[7] = (__bf16)v1.w;
    return o;
}

// ============================================================================
// GEMM1: HT[(b*8+h)*64+d][n] = sum_f X[b*512+n][f] * Wt[h*64+d][f]  (bf16 out)
// BM=64, BN=128, KC=64 -> grid 1024 (4 blocks/CU). Tt transpose buffer
// ALIASED over As/Bs (24 KB total LDS). XCD-chunked swizzle. Fused e1/e2.
// 256 thr = 4 waves (2 M-halves x 2 N-halves).
// ============================================================================
__global__ __launch_bounds__(256) void gemm1_f(
    const float* __restrict__ X, const float* __restrict__ Wt,
    __bf16* __restrict__ HT,
    const float* __restrict__ a1, const float* __restrict__ a2,
    float* __restrict__ E1, float* __restrict__ E2) {
    __shared__ char smem[24576];       // As[8K] | Bs[16K]; Tt[16K] aliases front
    char* As = smem;
    char* Bs = smem + 8192;
    char* Tt = smem;
    const int tid = threadIdx.x;
    const int w = tid >> 6, lane = tid & 63;
    const int wm = w >> 1, wn = w & 1;
    const int r = lane & 15, g = lane >> 4;
    const int L = blockIdx.x;
    const int W = (L & 7) * 128 + (L >> 3);   // XCD-chunked (1024 % 8 == 0)
    const int m_tile = W >> 2, n_tile = W & 3;
    const int m0 = m_tile * 64;
    const int n0 = n_tile * 128;

    f32x4 acc[2][4];
#pragma unroll
    for (int mt = 0; mt < 2; ++mt)
#pragma unroll
        for (int nt = 0; nt < 4; ++nt) {
            acc[mt][nt][0] = 0.f; acc[mt][nt][1] = 0.f;
            acc[mt][nt][2] = 0.f; acc[mt][nt][3] = 0.f;
        }

    const int sr = tid >> 3;         // 0..31
    const int c8 = (tid & 7) * 8;    // float col within 64-chunk

    for (int k0 = 0; k0 < 256; k0 += 64) {
        __syncthreads();
#pragma unroll
        for (int i = 0; i < 2; ++i) {   // A: 64 rows
            int row = sr + i * 32;
            bf16x8 va = cvt8(X + (size_t)(m0 + row) * 256 + k0 + c8);
            *(bf16x8*)(As + row * 128 + ((c8 * 2) ^ ((row & 7) << 4))) = va;
        }
#pragma unroll
        for (int i = 0; i < 4; ++i) {   // B: 128 rows
            int row = sr + i * 32;
            bf16x8 vb = cvt8(Wt + (size_t)(n0 + row) * 256 + k0 + c8);
            *(bf16x8*)(Bs + row * 128 + ((c8 * 2) ^ ((row & 7) << 4))) = vb;
        }
        __syncthreads();
#pragma unroll
        for (int kk = 0; kk < 64; kk += 32) {
            bf16x8 af[2], bfv[4];
#pragma unroll
            for (int mt = 0; mt < 2; ++mt) {
                int row = wm * 32 + mt * 16 + r;
                af[mt] = *(const bf16x8*)(As + row * 128 +
                                          (((kk + g * 8) * 2) ^ ((row & 7) << 4)));
            }
#pragma unroll
            for (int nt = 0; nt < 4; ++nt) {
                int row = wn * 64 + nt * 16 + r;
                bfv[nt] = *(const bf16x8*)(Bs + row * 128 +
                                           (((kk + g * 8) * 2) ^ ((row & 7) << 4)));
            }
#pragma unroll
            for (int mt = 0; mt < 2; ++mt)
#pragma unroll
                for (int nt = 0; nt < 4; ++nt)
                    acc[mt][nt] = __builtin_amdgcn_mfma_f32_16x16x32_bf16(
                        af[mt], bfv[nt], acc[mt][nt], 0, 0, 0);
        }
    }

    // ---- transpose C tile through aliased Tt (barrier first: As/Bs dead) ----
    __syncthreads();
#pragma unroll
    for (int mt = 0; mt < 2; ++mt) {
        int node = wm * 32 + mt * 16 + g * 4;
#pragma unroll
        for (int nt = 0; nt < 4; ++nt) {
            int d_blk = wn * 64 + nt * 16 + r;
            bf16x4 pv;
#pragma unroll
            for (int reg = 0; reg < 4; ++reg) pv[reg] = (__bf16)acc[mt][nt][reg];
            *(bf16x4*)(Tt + ((d_blk * 128 + node * 2) ^ ((d_blk & 7) << 4))) = pv;
        }
    }
    __syncthreads();
    {   // coalesced bf16x8 stores: 128 d-rows x 64 nodes
        const int b = m0 >> 9, nn = m0 & 511;
        const int h0 = n_tile * 2;
        const int col = tid & 7;
#pragma unroll
        for (int i = 0; i < 4; ++i) {
            int d_row = (tid >> 3) + i * 32;
            int hrow = (b * 8 + h0 + (d_row >> 6)) * 64 + (d_row & 63);
            bf16x8 v = *(const bf16x8*)(Tt + ((d_row * 128 + col * 16) ^
                                              ((d_row & 7) << 4)));
            *(bf16x8*)(HT + (size_t)hrow * 512 + nn + col * 8) = v;
        }
    }
    // ---- e1/e2 ----
    const int h = n_tile * 2 + wn;
    float w1[4], w2[4];
#pragma unroll
    for (int nt = 0; nt < 4; ++nt) {
        w1[nt] = a1[h * 64 + nt * 16 + r];
        w2[nt] = a2[h * 64 + nt * 16 + r];
    }
#pragma unroll
    for (int mt = 0; mt < 2; ++mt)
#pragma unroll
        for (int reg = 0; reg < 4; ++reg) {
            float s1 = 0.f, s2 = 0.f;
#pragma unroll
            for (int nt = 0; nt < 4; ++nt) {
                s1 += acc[mt][nt][reg] * w1[nt];
                s2 += acc[mt][nt][reg] * w2[nt];
            }
#pragma unroll
            for (int off = 1; off <= 8; off <<= 1) {
                s1 += __shfl_xor(s1, off, 64);
                s2 += __shfl_xor(s2, off, 64);
            }
            if (r == 0) {
                int m = m0 + wm * 32 + mt * 16 + g * 4 + reg;
                int b = m >> 9, n = m & 511;
                E1[(size_t)(b * 8 + h) * 512 + n] = s1;
                E2[(size_t)(b * 8 + h) * 512 + n] = s2;
            }
        }
}

// ============================================================================
// attn: per (b,h,quarter): OL[j, h*64+d] = leaky_.01(softmax_j . H) in bf16.
// grid 1024 (4 blocks per bh), 256 thr. Per-chunk 4KB cooperative LDS stage
// of H^T with register prefetch of the next chunk.
// ============================================================================
__global__ __launch_bounds__(256) void attn_s(const __bf16* __restrict__ HT,
                                              const float* __restrict__ E1,
                                              const float* __restrict__ E2,
                                              __bf16* __restrict__ OL) {
    __shared__ char Hc[4096];        // [d][k-chunk of 32] bf16, XOR-swizzled
    __shared__ float e1s[512];
    __shared__ float redm[256];
    __shared__ float zrow[4][32];
    __shared__ float e1maxS;

    const int bid = blockIdx.x;
    const int bh = bid >> 2, qq = bid & 3;
    const int b = bh >> 3, h = bh & 7;
    const int tid = threadIdx.x;
    const int w = tid >> 6, lane = tid & 63;
    const int r = lane & 15, g = lane >> 4;

    for (int i = tid; i < 512; i += 256) e1s[i] = E1[(size_t)bh * 512 + i];
    __syncthreads();
    redm[tid] = fmaxf(e1s[tid], e1s[tid + 256]);
    __syncthreads();
    if (tid < 64) {
        float m = fmaxf(fmaxf(redm[tid], redm[tid + 64]),
                        fmaxf(redm[tid + 128], redm[tid + 192]));
#pragma unroll
        for (int off = 32; off >= 1; off >>= 1) m = fmaxf(m, __shfl_xor(m, off, 64));
        if (tid == 0) e1maxS = m;
    }
    __syncthreads();
    const float e1max = e1maxS;

    float ee2[2], mm[2];
    const float* e2g = E2 + (size_t)bh * 512 + qq * 128 + w * 32;
#pragma unroll
    for (int mt = 0; mt < 2; ++mt) {
        float v = e2g[mt * 16 + r];
        ee2[mt] = v;
        float s = e1max + v;
        mm[mt] = fmaxf(s, ALPHA * s);
    }

    f32x4 acc[2][4];
#pragma unroll
    for (int mt = 0; mt < 2; ++mt)
#pragma unroll
        for (int nt = 0; nt < 4; ++nt) {
            acc[mt][nt][0] = 0.f; acc[mt][nt][1] = 0.f;
            acc[mt][nt][2] = 0.f; acc[mt][nt][3] = 0.f;
        }
    float zac[2] = {0.f, 0.f};

    const int d_s = tid >> 2, kq = tid & 3;
    const __bf16* hsrc = HT + (size_t)(bh * 64 + d_s) * 512 + kq * 8;
    const int lw = d_s * 64 + ((kq * 16) ^ ((d_s & 3) << 4));
    bf16x8 stg = *(const bf16x8*)hsrc;

    for (int c = 0; c < 16; ++c) {
        __syncthreads();
        *(bf16x8*)(Hc + lw) = stg;
        __syncthreads();
        if (c < 15) stg = *(const bf16x8*)(hsrc + (c + 1) * 32);

        const float* ep = e1s + c * 32 + g * 8;
        float4 ea = *(const float4*)(ep);
        float4 eb = *(const float4*)(ep + 4);
        float e1c[8] = {ea.x, ea.y, ea.z, ea.w, eb.x, eb.y, eb.z, eb.w};

        bf16x8 bfr[4];
#pragma unroll
        for (int nt = 0; nt < 4; ++nt) {
            int d = nt * 16 + r;
            bfr[nt] = *(const bf16x8*)(Hc + d * 64 + ((g * 16) ^ ((d & 3) << 4)));
        }
#pragma unroll
        for (int mt = 0; mt < 2; ++mt) {
            bf16x8 af;
            float zp = 0.f;
#pragma unroll
            for (int q = 0; q < 8; ++q) {
                float s = e1c[q] + ee2[mt];
                s = fmaxf(s, ALPHA * s);
                float p = __expf(s - mm[mt]);
                zp += p;
                af[q] = (__bf16)p;
            }
            zac[mt] += zp;
#pragma unroll
            for (int nt = 0; nt < 4; ++nt)
                acc[mt][nt] =
                    __builtin_amdgcn_mfma_f32_16x16x32_bf16(af, bfr[nt], acc[mt][nt], 0, 0, 0);
        }
    }

#pragma unroll
    for (int mt = 0; mt < 2; ++mt) {
        float z = zac[mt];
        z += __shfl_xor(z, 16, 64);
        z += __shfl_xor(z, 32, 64);
        if (g == 0) zrow[w][mt * 16 + r] = 1.f / z;
    }

    __bf16* ob = OL + ((size_t)b * 512 + qq * 128 + w * 32) * 512 + h * 64;
#pragma unroll
    for (int mt = 0; mt < 2; ++mt) {
#pragma unroll
        for (int reg = 0; reg < 4; ++reg) {
            int row = mt * 16 + g * 4 + reg;
            float zi = zrow[w][row];
#pragma unroll
            for (int nt = 0; nt < 4; ++nt) {
                float v = acc[mt][nt][reg] * zi;
                v = fmaxf(v, ACVT * v);  // leaky 0.01 fused
                ob[(size_t)row * 512 + nt * 16 + r] = (__bf16)v;
            }
        }
    }
}

// ============================================================================
// GEMM2: H2[m][c] = sum_k OL[m][k] * Wo[c][k] (bf16 out), fused f1/f2.
// BM=32, BN=128, KC=64. grid 512.
// ============================================================================
__global__ __launch_bounds__(256) void gemm2_f(
    const __bf16* __restrict__ OL, const float* __restrict__ Wo,
    __bf16* __restrict__ H2,
    const float* __restrict__ a1o, const float* __restrict__ a2o,
    float* __restrict__ F1, float* __restrict__ F2) {
    __shared__ char As[32 * 128];
    __shared__ char Bs[128 * 128];
    __shared__ float fred[2][32][2];
    const int tid = threadIdx.x;
    const int w = tid >> 6, lane = tid & 63;
    const int wm = w >> 1, wn = w & 1;
    const int r = lane & 15, g = lane >> 4;
    const int m0 = blockIdx.x * 32;

    f32x4 acc[4];
#pragma unroll
    for (int nt = 0; nt < 4; ++nt) {
        acc[nt][0] = 0.f; acc[nt][1] = 0.f; acc[nt][2] = 0.f; acc[nt][3] = 0.f;
    }

    const int sra = tid >> 3;        // 0..31
    const int c8 = (tid & 7) * 8;

    for (int k0 = 0; k0 < 512; k0 += 64) {
        __syncthreads();
        {
            bf16x8 va = *(const bf16x8*)((const char*)OL +
                                         ((size_t)(m0 + sra) * 512 + k0) * 2 + c8 * 2);
            *(bf16x8*)(As + sra * 128 + ((c8 * 2) ^ ((sra & 7) << 4))) = va;
        }
#pragma unroll
        for (int i = 0; i < 4; ++i) {
            int row = sra + i * 32;
            bf16x8 vb = cvt8(Wo + (size_t)row * 512 + k0 + c8);
            *(bf16x8*)(Bs + row * 128 + ((c8 * 2) ^ ((row & 7) << 4))) = vb;
        }
        __syncthreads();
#pragma unroll
        for (int kk = 0; kk < 64; kk += 32) {
            int arow = wm * 16 + r;
            bf16x8 af = *(const bf16x8*)(As + arow * 128 +
                                         (((kk + g * 8) * 2) ^ ((arow & 7) << 4)));
            bf16x8 bfv[4];
#pragma unroll
            for (int nt = 0; nt < 4; ++nt) {
                int row = wn * 64 + nt * 16 + r;
                bfv[nt] = *(const bf16x8*)(Bs + row * 128 +
                                           (((kk + g * 8) * 2) ^ ((row & 7) << 4)));
            }
#pragma unroll
            for (int nt = 0; nt < 4; ++nt)
                acc[nt] = __builtin_amdgcn_mfma_f32_16x16x32_bf16(af, bfv[nt], acc[nt], 0, 0, 0);
        }
    }

#pragma unroll
    for (int reg = 0; reg < 4; ++reg) {
        int row = m0 + wm * 16 + g * 4 + reg;
#pragma unroll
        for (int nt = 0; nt < 4; ++nt)
            H2[(size_t)row * 128 + wn * 64 + nt * 16 + r] = (__bf16)acc[nt][reg];
    }
    float w1[4], w2[4];
#pragma unroll
    for (int nt = 0; nt < 4; ++nt) {
        w1[nt] = a1o[wn * 64 + nt * 16 + r];
        w2[nt] = a2o[wn * 64 + nt * 16 + r];
    }
#pragma unroll
    for (int reg = 0; reg < 4; ++reg) {
        float s1 = 0.f, s2 = 0.f;
#pragma unroll
        for (int nt = 0; nt < 4; ++nt) {
            s1 += acc[nt][reg] * w1[nt];
            s2 += acc[nt][reg] * w2[nt];
        }
#pragma unroll
        for (int off = 1; off <= 8; off <<= 1) {
            s1 += __shfl_xor(s1, off, 64);
            s2 += __shfl_xor(s2, off, 64);
        }
        if (r == 0) {
            int lr = wm * 16 + g * 4 + reg;
            fred[wn][lr][0] = s1;
            fred[wn][lr][1] = s2;
        }
    }
    __syncthreads();
    if (tid < 32) {
        int m = m0 + tid;
        int b = m >> 9, n = m & 511;
        F1[(size_t)b * 512 + n] = fred[0][tid][0] + fred[1][tid][0];
        F2[(size_t)b * 512 + n] = fred[0][tid][1] + fred[1][tid][1];
    }
}

// ============================================================================
// zw: per (b, jc): partial w[k] = sum_{j in chunk} softmax_k(leaky(f1+f2))[j,k]
// ============================================================================
__global__ __launch_bounds__(256) void zw_k(const float* __restrict__ F1,
                                            const float* __restrict__ F2,
                                            float* __restrict__ WP) {
    __shared__ float f1s[512];
    __shared__ float wpart[4][512];
    __shared__ float redm[256];
    const int b = blockIdx.x >> 4, jc = blockIdx.x & 15;
    const int tid = threadIdx.x;
    const int w = tid >> 6, lane = tid & 63;

    f1s[tid] = F1[(size_t)b * 512 + tid];
    f1s[tid + 256] = F1[(size_t)b * 512 + tid + 256];
#pragma unroll
    for (int i = 0; i < 8; ++i) wpart[w][lane + 64 * i] = 0.f;
    __syncthreads();
    redm[tid] = fmaxf(f1s[tid], f1s[tid + 256]);
    __syncthreads();
    if (tid < 64) {
        float m = fmaxf(fmaxf(redm[tid], redm[tid + 64]), fmaxf(redm[tid + 128], redm[tid + 192]));
#pragma unroll
        for (int off = 32; off >= 1; off >>= 1) m = fmaxf(m, __shfl_xor(m, off, 64));
        if (tid == 0) redm[0] = m;
    }
    __syncthreads();
    const float f1m = redm[0];

    for (int jj = 0; jj < 8; ++jj) {
        int j = jc * 32 + w * 8 + jj;
        float f2j = F2[(size_t)b * 512 + j];
        float sj = f1m + f2j;
        float mj = fmaxf(sj, ALPHA * sj);
        float pv[8];
        float z = 0.f;
#pragma unroll
        for (int i = 0; i < 8; ++i) {
            float s = f1s[lane + 64 * i] + f2j;
            s = fmaxf(s, ALPHA * s);
            float p = __expf(s - mj);
            pv[i] = p;
            z += p;
        }
#pragma unroll
        for (int off = 32; off >= 1; off >>= 1) z += __shfl_xor(z, off, 64);
        float inv = 1.f / z;
#pragma unroll
        for (int i = 0; i < 8; ++i) wpart[w][lane + 64 * i] += pv[i] * inv;
    }
    __syncthreads();
    for (int i = tid; i < 512; i += 256)
        WP[(size_t)(b * 16 + jc) * 512 + i] =
            wpart[0][i] + wpart[1][i] + wpart[2][i] + wpart[3][i];
}

// ============================================================================
// finalv: per b: w = sum WP; v = (w/512) . H2; out = normalize(v @ Wl^T + bl)
// ============================================================================
__global__ __launch_bounds__(512) void finalv_k(const float* __restrict__ WP,
                                                const __bf16* __restrict__ H2,
                                                const float* __restrict__ Wl,
                                                const float* __restrict__ bl,
                                                float* __restrict__ out) {
    __shared__ float wsL[512];
    __shared__ float part[4][128];
    __shared__ float vs[128];
    __shared__ float fo_s[128];
    __shared__ float r0;
    const int b = blockIdx.x, tid = threadIdx.x;
    {
        float s = 0.f;
#pragma unroll
        for (int jc = 0; jc < 16; ++jc) s += WP[(size_t)(b * 16 + jc) * 512 + tid];
        wsL[tid] = s;
    }
    __syncthreads();
    {
        const int q = tid >> 7, d = tid & 127;
        const __bf16* h2p = H2 + ((size_t)b * 512 + q * 128) * 128 + d;
        float acc = 0.f;
#pragma unroll 8
        for (int i = 0; i < 128; ++i) acc += wsL[q * 128 + i] * (float)h2p[(size_t)i * 128];
        part[q][d] = acc;
    }
    __syncthreads();
    if (tid < 128)
        vs[tid] = (part[0][tid] + part[1][tid] + part[2][tid] + part[3][tid]) * (1.f / 512.f);
    __syncthreads();
    if (tid < 128) {
        float fo = bl[tid];
        const float* wl = Wl + (size_t)tid * 128;
#pragma unroll 4
        for (int d = 0; d < 128; d += 4)
            fo += vs[d] * wl[d] + vs[d + 1] * wl[d + 1] + vs[d + 2] * wl[d + 2] +
                  vs[d + 3] * wl[d + 3];
        fo_s[tid] = fo;
    }
    __syncthreads();
    if (tid < 64) {
        float s = fo_s[tid] * fo_s[tid] + fo_s[tid + 64] * fo_s[tid + 64];
#pragma unroll
        for (int off = 32; off >= 1; off >>= 1) s += __shfl_xor(s, off, 64);
        if (tid == 0) r0 = s;
    }
    __syncthreads();
    float inv = 1.f / fmaxf(sqrtf(r0), 1e-12f);
    if (tid < 128) out[(size_t)b * 128 + tid] = fo_s[tid] * inv;
}

extern "C" void kernel_launch(void* const* d_in, const int* in_sizes, int n_in,
                              void* d_out, int out_size, void* d_ws, size_t ws_size,
                              hipStream_t stream) {
    const float* X = (const float*)d_in[0];
    const float* Wt = (const float*)d_in[1];
    const float* a1 = (const float*)d_in[2];
    const float* a2 = (const float*)d_in[3];
    const float* Wo = (const float*)d_in[4];
    const float* a1o = (const float*)d_in[5];
    const float* a2o = (const float*)d_in[6];
    const float* Wl = (const float*)d_in[7];
    const float* bl = (const float*)d_in[8];
    float* out = (float*)d_out;

    char* p = (char*)d_ws;
    __bf16* HT = (__bf16*)p;  p += (size_t)8388608 * 2;   // 16 MB
    __bf16* OL = (__bf16*)p;  p += (size_t)8388608 * 2;   // 16 MB
    float* E1 = (float*)p;    p += (size_t)131072 * 4;
    float* E2 = (float*)p;    p += (size_t)131072 * 4;
    __bf16* H2 = (__bf16*)p;  p += (size_t)2097152 * 2;   // 4 MB
    float* F1 = (float*)p;    p += (size_t)16384 * 4;
    float* F2 = (float*)p;    p += (size_t)16384 * 4;
    float* WP = (float*)p;    p += (size_t)262144 * 4;    // 1 MB

    gemm1_f<<<1024, 256, 0, stream>>>(X, Wt, HT, a1, a2, E1, E2);
    attn_s<<<1024, 256, 0, stream>>>(HT, E1, E2, OL);
    gemm2_f<<<512, 256, 0, stream>>>(OL, Wo, H2, a1o, a2o, F1, F2);
    zw_k<<<512, 256, 0, stream>>>(F1, F2, WP);
    finalv_k<<<32, 512, 0, stream>>>(WP, H2, Wl, bl, out);
}

// Round 10
// 142.158 us; speedup vs baseline: 1.2561x; 1.0252x over previous
//
#include <hip/hip_runtime.h>
#include <hip/hip_bf16.h>
#include <math.h>

#define ALPHA 0.2f
#define ACVT 0.01f

typedef __attribute__((ext_vector_type(8))) __bf16 bf16x8;
typedef __attribute__((ext_vector_type(4))) __bf16 bf16x4;
typedef __attribute__((ext_vector_type(4))) float f32x4;

__device__ __forceinline__ bf16x8 cvt8(const float* p) {
    float4 v0 = *(const float4*)p;
    float4 v1 = *(const float4*)(p + 4);
    bf16x8 o;
    o[0] = (__bf16)v0.x; o[1] = (__bf16)v0.y; o[2] = (__bf16)v0.z; o[3] = (__bf16)v0.w;
    o[4] = (__bf16)v1.x; o[5] = (__bf16)v1.y; o[6] = (__bf16)v1.z; o[7] = (__bf16)v1.w;
    return o;
}

// ============================================================================
// GEMM1 (round-6 best): HT[(b*8+h)*64+d][n] = sum_f X[n][f]*Wt[h*64+d][f]
// BM=BN=128, KC=64, grid 512 XCD-chunked. HT store via padded LDS transpose.
// Fused e1/e2.
// ============================================================================
__global__ __launch_bounds__(256) void gemm1_f(
    const float* __restrict__ X, const float* __restrict__ Wt,
    __bf16* __restrict__ HT,
    const float* __restrict__ a1, const float* __restrict__ a2,
    float* __restrict__ E1, float* __restrict__ E2) {
    __shared__ char As[128 * 128];
    __shared__ char Bs[128 * 128];
    __shared__ char Tt[128 * 264];
    const int tid = threadIdx.x;
    const int w = tid >> 6, lane = tid & 63;
    const int wm = w >> 1, wn = w & 1;
    const int r = lane & 15, g = lane >> 4;
    const int L = blockIdx.x;
    const int W = (L & 7) * 64 + (L >> 3);
    const int m_tile = W >> 2, n_tile = W & 3;
    const int m0 = m_tile * 128;
    const int n0 = n_tile * 128;

    f32x4 acc[4][4];
#pragma unroll
    for (int mt = 0; mt < 4; ++mt)
#pragma unroll
        for (int nt = 0; nt < 4; ++nt) {
            acc[mt][nt][0] = 0.f; acc[mt][nt][1] = 0.f;
            acc[mt][nt][2] = 0.f; acc[mt][nt][3] = 0.f;
        }

    const int sr = tid >> 3;
    const int c8 = (tid & 7) * 8;

    for (int k0 = 0; k0 < 256; k0 += 64) {
        __syncthreads();
#pragma unroll
        for (int i = 0; i < 4; ++i) {
            int row = sr + i * 32;
            bf16x8 va = cvt8(X + (size_t)(m0 + row) * 256 + k0 + c8);
            *(bf16x8*)(As + row * 128 + ((c8 * 2) ^ ((row & 7) << 4))) = va;
            bf16x8 vb = cvt8(Wt + (size_t)(n0 + row) * 256 + k0 + c8);
            *(bf16x8*)(Bs + row * 128 + ((c8 * 2) ^ ((row & 7) << 4))) = vb;
        }
        __syncthreads();
#pragma unroll
        for (int kk = 0; kk < 64; kk += 32) {
            bf16x8 af[4], bfv[4];
#pragma unroll
            for (int mt = 0; mt < 4; ++mt) {
                int row = wm * 64 + mt * 16 + r;
                af[mt] = *(const bf16x8*)(As + row * 128 +
                                          (((kk + g * 8) * 2) ^ ((row & 7) << 4)));
            }
#pragma unroll
            for (int nt = 0; nt < 4; ++nt) {
                int row = wn * 64 + nt * 16 + r;
                bfv[nt] = *(const bf16x8*)(Bs + row * 128 +
                                           (((kk + g * 8) * 2) ^ ((row & 7) << 4)));
            }
#pragma unroll
            for (int mt = 0; mt < 4; ++mt)
#pragma unroll
                for (int nt = 0; nt < 4; ++nt)
                    acc[mt][nt] = __builtin_amdgcn_mfma_f32_16x16x32_bf16(
                        af[mt], bfv[nt], acc[mt][nt], 0, 0, 0);
        }
    }

#pragma unroll
    for (int mt = 0; mt < 4; ++mt) {
        int node = wm * 64 + mt * 16 + g * 4;
#pragma unroll
        for (int nt = 0; nt < 4; ++nt) {
            int d_blk = wn * 64 + nt * 16 + r;
            bf16x4 pv;
#pragma unroll
            for (int reg = 0; reg < 4; ++reg) pv[reg] = (__bf16)acc[mt][nt][reg];
            *(bf16x4*)(Tt + d_blk * 264 + node * 2) = pv;
        }
    }
    __syncthreads();
    {
        const int b = m0 >> 9, nn = m0 & 511;
        const int h0 = n_tile * 2;
#pragma unroll
        for (int i = 0; i < 8; ++i) {
            int d_row = (tid >> 4) + i * 16;
            int hrow = (b * 8 + h0 + (d_row >> 6)) * 64 + (d_row & 63);
            bf16x8 v = *(const bf16x8*)(Tt + d_row * 264 + (tid & 15) * 16);
            *(bf16x8*)(HT + (size_t)hrow * 512 + nn + (tid & 15) * 8) = v;
        }
    }
    const int h = n_tile * 2 + wn;
    float w1[4], w2[4];
#pragma unroll
    for (int nt = 0; nt < 4; ++nt) {
        w1[nt] = a1[h * 64 + nt * 16 + r];
        w2[nt] = a2[h * 64 + nt * 16 + r];
    }
#pragma unroll
    for (int mt = 0; mt < 4; ++mt)
#pragma unroll
        for (int reg = 0; reg < 4; ++reg) {
            float s1 = 0.f, s2 = 0.f;
#pragma unroll
            for (int nt = 0; nt < 4; ++nt) {
                s1 += acc[mt][nt][reg] * w1[nt];
                s2 += acc[mt][nt][reg] * w2[nt];
            }
#pragma unroll
            for (int off = 1; off <= 8; off <<= 1) {
                s1 += __shfl_xor(s1, off, 64);
                s2 += __shfl_xor(s2, off, 64);
            }
            if (r == 0) {
                int m = m0 + wm * 64 + mt * 16 + g * 4 + reg;
                int b = m >> 9, n = m & 511;
                E1[(size_t)(b * 8 + h) * 512 + n] = s1;
                E2[(size_t)(b * 8 + h) * 512 + n] = s2;
            }
        }
}

// ============================================================================
// attn: per (b,h,quarter). Ping-pong double-buffered H^T staging:
// issue next-chunk load BEFORE compute, write to idle buffer after,
// ONE barrier per chunk (16 vs 32). grid 1024, 256 thr.
// ============================================================================
__global__ __launch_bounds__(256) void attn_s(const __bf16* __restrict__ HT,
                                              const float* __restrict__ E1,
                                              const float* __restrict__ E2,
                                              __bf16* __restrict__ OL) {
    __shared__ char Hc0[4096];
    __shared__ char Hc1[4096];
    __shared__ float e1s[512];
    __shared__ float redm[256];
    __shared__ float zrow[4][32];
    __shared__ float e1maxS;

    const int bid = blockIdx.x;
    const int bh = bid >> 2, qq = bid & 3;
    const int b = bh >> 3, h = bh & 7;
    const int tid = threadIdx.x;
    const int w = tid >> 6, lane = tid & 63;
    const int r = lane & 15, g = lane >> 4;

    for (int i = tid; i < 512; i += 256) e1s[i] = E1[(size_t)bh * 512 + i];
    __syncthreads();
    redm[tid] = fmaxf(e1s[tid], e1s[tid + 256]);
    __syncthreads();
    if (tid < 64) {
        float m = fmaxf(fmaxf(redm[tid], redm[tid + 64]),
                        fmaxf(redm[tid + 128], redm[tid + 192]));
#pragma unroll
        for (int off = 32; off >= 1; off >>= 1) m = fmaxf(m, __shfl_xor(m, off, 64));
        if (tid == 0) e1maxS = m;
    }
    __syncthreads();
    const float e1max = e1maxS;

    float ee2[2], mm[2];
    const float* e2g = E2 + (size_t)bh * 512 + qq * 128 + w * 32;
#pragma unroll
    for (int mt = 0; mt < 2; ++mt) {
        float v = e2g[mt * 16 + r];
        ee2[mt] = v;
        float s = e1max + v;
        mm[mt] = fmaxf(s, ALPHA * s);
    }

    f32x4 acc[2][4];
#pragma unroll
    for (int mt = 0; mt < 2; ++mt)
#pragma unroll
        for (int nt = 0; nt < 4; ++nt) {
            acc[mt][nt][0] = 0.f; acc[mt][nt][1] = 0.f;
            acc[mt][nt][2] = 0.f; acc[mt][nt][3] = 0.f;
        }
    float zac[2] = {0.f, 0.f};

    // staging: thread -> (d = tid>>2, k-quad = tid&3), 16B/chunk each
    const int d_s = tid >> 2, kq = tid & 3;
    const __bf16* hsrc = HT + (size_t)(bh * 64 + d_s) * 512 + kq * 8;
    const int lwo = d_s * 64 + ((kq * 16) ^ ((d_s & 3) << 4));
    char* cur = Hc0;
    char* nxt = Hc1;
    *(bf16x8*)(cur + lwo) = *(const bf16x8*)hsrc;
    __syncthreads();

    for (int c = 0; c < 16; ++c) {
        bf16x8 stg;
        if (c < 15) stg = *(const bf16x8*)(hsrc + (c + 1) * 32);  // issue early

        const float* ep = e1s + c * 32 + g * 8;
        float4 ea = *(const float4*)(ep);
        float4 eb = *(const float4*)(ep + 4);
        float e1c[8] = {ea.x, ea.y, ea.z, ea.w, eb.x, eb.y, eb.z, eb.w};

        bf16x8 bfr[4];
#pragma unroll
        for (int nt = 0; nt < 4; ++nt) {
            int d = nt * 16 + r;
            bfr[nt] = *(const bf16x8*)(cur + d * 64 + ((g * 16) ^ ((d & 3) << 4)));
        }
#pragma unroll
        for (int mt = 0; mt < 2; ++mt) {
            bf16x8 af;
            float zp = 0.f;
#pragma unroll
            for (int q = 0; q < 8; ++q) {
                float s = e1c[q] + ee2[mt];
                s = fmaxf(s, ALPHA * s);
                float p = __expf(s - mm[mt]);
                zp += p;
                af[q] = (__bf16)p;
            }
            zac[mt] += zp;
#pragma unroll
            for (int nt = 0; nt < 4; ++nt)
                acc[mt][nt] =
                    __builtin_amdgcn_mfma_f32_16x16x32_bf16(af, bfr[nt], acc[mt][nt], 0, 0, 0);
        }

        if (c < 15) *(bf16x8*)(nxt + lwo) = stg;  // write to idle buffer
        __syncthreads();                          // one barrier per chunk
        char* t = cur; cur = nxt; nxt = t;
    }

#pragma unroll
    for (int mt = 0; mt < 2; ++mt) {
        float z = zac[mt];
        z += __shfl_xor(z, 16, 64);
        z += __shfl_xor(z, 32, 64);
        if (g == 0) zrow[w][mt * 16 + r] = 1.f / z;
    }

    __bf16* ob = OL + ((size_t)b * 512 + qq * 128 + w * 32) * 512 + h * 64;
#pragma unroll
    for (int mt = 0; mt < 2; ++mt) {
#pragma unroll
        for (int reg = 0; reg < 4; ++reg) {
            int row = mt * 16 + g * 4 + reg;
            float zi = zrow[w][row];
#pragma unroll
            for (int nt = 0; nt < 4; ++nt) {
                float v = acc[mt][nt][reg] * zi;
                v = fmaxf(v, ACVT * v);  // leaky 0.01 fused
                ob[(size_t)row * 512 + nt * 16 + r] = (__bf16)v;
            }
        }
    }
}

// ============================================================================
// GEMM2: H2[m][c] = sum_k OL[m][k] * Wo[c][k] (bf16 out), fused f1/f2.
// BM=32, BN=128, KC=64. grid 512.
// ============================================================================
__global__ __launch_bounds__(256) void gemm2_f(
    const __bf16* __restrict__ OL, const float* __restrict__ Wo,
    __bf16* __restrict__ H2,
    const float* __restrict__ a1o, const float* __restrict__ a2o,
    float* __restrict__ F1, float* __restrict__ F2) {
    __shared__ char As[32 * 128];
    __shared__ char Bs[128 * 128];
    __shared__ float fred[2][32][2];
    const int tid = threadIdx.x;
    const int w = tid >> 6, lane = tid & 63;
    const int wm = w >> 1, wn = w & 1;
    const int r = lane & 15, g = lane >> 4;
    const int m0 = blockIdx.x * 32;

    f32x4 acc[4];
#pragma unroll
    for (int nt = 0; nt < 4; ++nt) {
        acc[nt][0] = 0.f; acc[nt][1] = 0.f; acc[nt][2] = 0.f; acc[nt][3] = 0.f;
    }

    const int sra = tid >> 3;
    const int c8 = (tid & 7) * 8;

    for (int k0 = 0; k0 < 512; k0 += 64) {
        __syncthreads();
        {
            bf16x8 va = *(const bf16x8*)((const char*)OL +
                                         ((size_t)(m0 + sra) * 512 + k0) * 2 + c8 * 2);
            *(bf16x8*)(As + sra * 128 + ((c8 * 2) ^ ((sra & 7) << 4))) = va;
        }
#pragma unroll
        for (int i = 0; i < 4; ++i) {
            int row = sra + i * 32;
            bf16x8 vb = cvt8(Wo + (size_t)row * 512 + k0 + c8);
            *(bf16x8*)(Bs + row * 128 + ((c8 * 2) ^ ((row & 7) << 4))) = vb;
        }
        __syncthreads();
#pragma unroll
        for (int kk = 0; kk < 64; kk += 32) {
            int arow = wm * 16 + r;
            bf16x8 af = *(const bf16x8*)(As + arow * 128 +
                                         (((kk + g * 8) * 2) ^ ((arow & 7) << 4)));
            bf16x8 bfv[4];
#pragma unroll
            for (int nt = 0; nt < 4; ++nt) {
                int row = wn * 64 + nt * 16 + r;
                bfv[nt] = *(const bf16x8*)(Bs + row * 128 +
                                           (((kk + g * 8) * 2) ^ ((row & 7) << 4)));
            }
#pragma unroll
            for (int nt = 0; nt < 4; ++nt)
                acc[nt] = __builtin_amdgcn_mfma_f32_16x16x32_bf16(af, bfv[nt], acc[nt], 0, 0, 0);
        }
    }

#pragma unroll
    for (int reg = 0; reg < 4; ++reg) {
        int row = m0 + wm * 16 + g * 4 + reg;
#pragma unroll
        for (int nt = 0; nt < 4; ++nt)
            H2[(size_t)row * 128 + wn * 64 + nt * 16 + r] = (__bf16)acc[nt][reg];
    }
    float w1[4], w2[4];
#pragma unroll
    for (int nt = 0; nt < 4; ++nt) {
        w1[nt] = a1o[wn * 64 + nt * 16 + r];
        w2[nt] = a2o[wn * 64 + nt * 16 + r];
    }
#pragma unroll
    for (int reg = 0; reg < 4; ++reg) {
        float s1 = 0.f, s2 = 0.f;
#pragma unroll
        for (int nt = 0; nt < 4; ++nt) {
            s1 += acc[nt][reg] * w1[nt];
            s2 += acc[nt][reg] * w2[nt];
        }
#pragma unroll
        for (int off = 1; off <= 8; off <<= 1) {
            s1 += __shfl_xor(s1, off, 64);
            s2 += __shfl_xor(s2, off, 64);
        }
        if (r == 0) {
            int lr = wm * 16 + g * 4 + reg;
            fred[wn][lr][0] = s1;
            fred[wn][lr][1] = s2;
        }
    }
    __syncthreads();
    if (tid < 32) {
        int m = m0 + tid;
        int b = m >> 9, n = m & 511;
        F1[(size_t)b * 512 + n] = fred[0][tid][0] + fred[1][tid][0];
        F2[(size_t)b * 512 + n] = fred[0][tid][1] + fred[1][tid][1];
    }
}

// ============================================================================
// zw: per (b, jc): partial w[k] = sum_{j in chunk} softmax_k(leaky(f1+f2))[j,k]
// ============================================================================
__global__ __launch_bounds__(256) void zw_k(const float* __restrict__ F1,
                                            const float* __restrict__ F2,
                                            float* __restrict__ WP) {
    __shared__ float f1s[512];
    __shared__ float wpart[4][512];
    __shared__ float redm[256];
    const int b = blockIdx.x >> 4, jc = blockIdx.x & 15;
    const int tid = threadIdx.x;
    const int w = tid >> 6, lane = tid & 63;

    f1s[tid] = F1[(size_t)b * 512 + tid];
    f1s[tid + 256] = F1[(size_t)b * 512 + tid + 256];
#pragma unroll
    for (int i = 0; i < 8; ++i) wpart[w][lane + 64 * i] = 0.f;
    __syncthreads();
    redm[tid] = fmaxf(f1s[tid], f1s[tid + 256]);
    __syncthreads();
    if (tid < 64) {
        float m = fmaxf(fmaxf(redm[tid], redm[tid + 64]), fmaxf(redm[tid + 128], redm[tid + 192]));
#pragma unroll
        for (int off = 32; off >= 1; off >>= 1) m = fmaxf(m, __shfl_xor(m, off, 64));
        if (tid == 0) redm[0] = m;
    }
    __syncthreads();
    const float f1m = redm[0];

    for (int jj = 0; jj < 8; ++jj) {
        int j = jc * 32 + w * 8 + jj;
        float f2j = F2[(size_t)b * 512 + j];
        float sj = f1m + f2j;
        float mj = fmaxf(sj, ALPHA * sj);
        float pv[8];
        float z = 0.f;
#pragma unroll
        for (int i = 0; i < 8; ++i) {
            float s = f1s[lane + 64 * i] + f2j;
            s = fmaxf(s, ALPHA * s);
            float p = __expf(s - mj);
            pv[i] = p;
            z += p;
        }
#pragma unroll
        for (int off = 32; off >= 1; off >>= 1) z += __shfl_xor(z, off, 64);
        float inv = 1.f / z;
#pragma unroll
        for (int i = 0; i < 8; ++i) wpart[w][lane + 64 * i] += pv[i] * inv;
    }
    __syncthreads();
    for (int i = tid; i < 512; i += 256)
        WP[(size_t)(b * 16 + jc) * 512 + i] =
            wpart[0][i] + wpart[1][i] + wpart[2][i] + wpart[3][i];
}

// ============================================================================
// finalv: per b: w = sum WP; v = (w/512) . H2; out = normalize(v @ Wl^T + bl)
// ============================================================================
__global__ __launch_bounds__(512) void finalv_k(const float* __restrict__ WP,
                                                const __bf16* __restrict__ H2,
                                                const float* __restrict__ Wl,
                                                const float* __restrict__ bl,
                                                float* __restrict__ out) {
    __shared__ float wsL[512];
    __shared__ float part[4][128];
    __shared__ float vs[128];
    __shared__ float fo_s[128];
    __shared__ float r0;
    const int b = blockIdx.x, tid = threadIdx.x;
    {
        float s = 0.f;
#pragma unroll
        for (int jc = 0; jc < 16; ++jc) s += WP[(size_t)(b * 16 + jc) * 512 + tid];
        wsL[tid] = s;
    }
    __syncthreads();
    {
        const int q = tid >> 7, d = tid & 127;
        const __bf16* h2p = H2 + ((size_t)b * 512 + q * 128) * 128 + d;
        float acc = 0.f;
#pragma unroll 8
        for (int i = 0; i < 128; ++i) acc += wsL[q * 128 + i] * (float)h2p[(size_t)i * 128];
        part[q][d] = acc;
    }
    __syncthreads();
    if (tid < 128)
        vs[tid] = (part[0][tid] + part[1][tid] + part[2][tid] + part[3][tid]) * (1.f / 512.f);
    __syncthreads();
    if (tid < 128) {
        float fo = bl[tid];
        const float* wl = Wl + (size_t)tid * 128;
#pragma unroll 4
        for (int d = 0; d < 128; d += 4)
            fo += vs[d] * wl[d] + vs[d + 1] * wl[d + 1] + vs[d + 2] * wl[d + 2] +
                  vs[d + 3] * wl[d + 3];
        fo_s[tid] = fo;
    }
    __syncthreads();
    if (tid < 64) {
        float s = fo_s[tid] * fo_s[tid] + fo_s[tid + 64] * fo_s[tid + 64];
#pragma unroll
        for (int off = 32; off >= 1; off >>= 1) s += __shfl_xor(s, off, 64);
        if (tid == 0) r0 = s;
    }
    __syncthreads();
    float inv = 1.f / fmaxf(sqrtf(r0), 1e-12f);
    if (tid < 128) out[(size_t)b * 128 + tid] = fo_s[tid] * inv;
}

extern "C" void kernel_launch(void* const* d_in, const int* in_sizes, int n_in,
                              void* d_out, int out_size, void* d_ws, size_t ws_size,
                              hipStream_t stream) {
    const float* X = (const float*)d_in[0];
    const float* Wt = (const float*)d_in[1];
    const float* a1 = (const float*)d_in[2];
    const float* a2 = (const float*)d_in[3];
    const float* Wo = (const float*)d_in[4];
    const float* a1o = (const float*)d_in[5];
    const float* a2o = (const float*)d_in[6];
    const float* Wl = (const float*)d_in[7];
    const float* bl = (const float*)d_in[8];
    float* out = (float*)d_out;

    char* p = (char*)d_ws;
    __bf16* HT = (__bf16*)p;  p += (size_t)8388608 * 2;   // 16 MB
    __bf16* OL = (__bf16*)p;  p += (size_t)8388608 * 2;   // 16 MB
    float* E1 = (float*)p;    p += (size_t)131072 * 4;
    float* E2 = (float*)p;    p += (size_t)131072 * 4;
    __bf16* H2 = (__bf16*)p;  p += (size_t)2097152 * 2;   // 4 MB
    float* F1 = (float*)p;    p += (size_t)16384 * 4;
    float* F2 = (float*)p;    p += (size_t)16384 * 4;
    float* WP = (float*)p;    p += (size_t)262144 * 4;    // 1 MB

    gemm1_f<<<512, 256, 0, stream>>>(X, Wt, HT, a1, a2, E1, E2);
    attn_s<<<1024, 256, 0, stream>>>(HT, E1, E2, OL);
    gemm2_f<<<512, 256, 0, stream>>>(OL, Wo, H2, a1o, a2o, F1, F2);
    zw_k<<<512, 256, 0, stream>>>(F1, F2, WP);
    finalv_k<<<32, 512, 0, stream>>>(WP, H2, Wl, bl, out);
}